// Round 19
// baseline (38.810 us; speedup 1.0000x reference)
//
#include <hip/hip_runtime.h>
#include <hip/hip_bf16.h>

#define FFN 2048
#define LN_EPS 1e-5f
#define REP_STRIDE 5376   // uint4s per table replica (86016 B)

typedef __attribute__((ext_vector_type(8))) short bf16x8;
typedef __attribute__((ext_vector_type(4))) short bf16x4;
typedef __attribute__((ext_vector_type(4))) float f32x4;

union FragU  { bf16x8 v; unsigned u[4]; uint4 q; };
union Frag2U { bf16x4 v; unsigned u[2]; uint2 d; };

static __device__ __forceinline__ unsigned cvtpk(float lo, float hi) {
    unsigned r;
    asm("v_cvt_pk_bf16_f32 %0, %1, %2" : "=v"(r) : "v"(lo), "v"(hi));
    return r;
}
static __device__ __forceinline__ ushort to_bf16(float f) {   // RNE, finite inputs
    unsigned u = __float_as_uint(f);
    u += 0x7fffu + ((u >> 16) & 1u);
    return (ushort)(u >> 16);
}
static __device__ __forceinline__ float frombf(ushort u) {
    return __uint_as_float((unsigned)u << 16);
}
static __device__ __forceinline__ unsigned pk2u(ushort a, ushort b) {
    return (unsigned)a | ((unsigned)b << 16);
}

// Per-replica ws layout (R16-verified values), replica r at ws + r*REP_STRIDE:
//  uint4  [0 .. 2111]     pW2 recs (33 uint4; bf16(W2/2), permuted k)
//  uint2  [4224 .. 10623] pW1x16 recs (50 uint2; W1 + b1 row, x16 A-frag layout)
//  float  [21248..21319]  M[e*9+k]
__global__ __launch_bounds__(256) void tbq_prep(
    const float* __restrict__ W1, const float* __restrict__ b1,
    const float* __restrict__ W2, uint4* __restrict__ ws)
{
    const int rep = blockIdx.x / 52;
    const int b   = blockIdx.x % 52;
    uint4* wsr = ws + rep * REP_STRIDE;

    if (b < 34) {
        const int idx = b * 256 + threadIdx.x;
        if (idx < 2112) {                       // pW2 records
            const int rec = idx / 33, r = idx % 33;
            ushort v[8] = {0,0,0,0,0,0,0,0};
            if (r) {
                const int l32 = r - 1, g = l32 >> 3, c = l32 & 7, cc = rec;
                #pragma unroll
                for (int j = 0; j < 8; ++j) {
                    const int fl = 4 * g + (j & 3) + 16 * (j >> 2);
                    v[j] = to_bf16(0.5f * W2[c * FFN + cc * 32 + fl]);
                }
            }
            union { ushort s[8]; uint4 q; } pk;
            #pragma unroll
            for (int j = 0; j < 8; ++j) pk.s[j] = v[j];
            wsr[idx] = pk.q;
        } else if (idx < 8512) {                // pW1x16 records
            const int i2 = idx - 2112;
            const int rec = i2 / 50, r = i2 % 50;
            const int s = rec & 1, cc = rec >> 1;
            uint2 val = make_uint2(0u, 0u);
            if (r >= 1 && r <= 32) {
                const int l32 = r - 1, c = l32 & 15, gg = l32 >> 4;
                const int f = cc * 32 + s * 16 + c;
                val.x = pk2u(to_bf16(W1[f * 8 + 4 * gg + 0]), to_bf16(W1[f * 8 + 4 * gg + 1]));
                val.y = pk2u(to_bf16(W1[f * 8 + 4 * gg + 2]), to_bf16(W1[f * 8 + 4 * gg + 3]));
            } else if (r >= 33 && r <= 48) {
                const int c = r - 33;
                const int f = cc * 32 + s * 16 + c;
                val.x = pk2u(to_bf16(b1[f]), 0);
            }
            ((uint2*)wsr)[4224 + i2] = val;
        }
    } else {                                    // M reduction
        const int w = (b - 34) * 4 + (threadIdx.x >> 6);   // 0..71
        const int lane = threadIdx.x & 63;
        const int e = w / 9, k = w % 9;
        float acc = 0.0f;
        #pragma unroll 4
        for (int i = 0; i < 32; ++i) {
            const int f = lane + i * 64;
            const float w2v = frombf(to_bf16(0.5f * W2[e * FFN + f]));
            const float ov  = (k < 8) ? frombf(to_bf16(W1[f * 8 + k]))
                                      : frombf(to_bf16(b1[f]));
            acc += w2v * ov;
        }
        #pragma unroll
        for (int m = 32; m >= 1; m >>= 1) acc += __shfl_xor(acc, m, 64);
        if (lane == 0) ((float*)wsr)[21248 + w] = acc;
    }
}

// T-bodies (R16-verified): 2x GEMM1(16x16x16, K=9 of 16) -> |.|+bf16 pack -> GEMM2(16x16x32).
#define TB_A(ACC, F0V, F1V, A2V, B1V)                                                  \
    asm volatile(                                                                      \
        "v_mfma_f32_16x16x16_bf16 v[40:43], %[f0], %[b1], %[z]\n\t"                    \
        "v_mfma_f32_16x16x16_bf16 v[44:47], %[f1], %[b1], %[z]\n\t"                    \
        "s_nop 7\n\t"                                                                  \
        "s_nop 7\n\t"                                                                  \
        "v_cvt_pk_bf16_f32 v48, |v40|, |v41|\n\t"                                      \
        "v_cvt_pk_bf16_f32 v49, |v42|, |v43|\n\t"                                      \
        "v_cvt_pk_bf16_f32 v50, |v44|, |v45|\n\t"                                      \
        "v_cvt_pk_bf16_f32 v51, |v46|, |v47|\n\t"                                      \
        "s_nop 3\n\t"                                                                  \
        "v_mfma_f32_16x16x32_bf16 %[acc], %[a2], v[48:51], %[acc]"                     \
        : [acc] "+v"(ACC)                                                              \
        : [f0] "v"(F0V), [f1] "v"(F1V), [a2] "v"(A2V), [b1] "v"(B1V), [z] "v"(z4)      \
        : "v40","v41","v42","v43","v44","v45","v46","v47","v48","v49","v50","v51")

#define TB_B(ACC, F0V, F1V, A2V, B1V)                                                  \
    asm volatile(                                                                      \
        "v_mfma_f32_16x16x16_bf16 v[52:55], %[f0], %[b1], %[z]\n\t"                    \
        "v_mfma_f32_16x16x16_bf16 v[56:59], %[f1], %[b1], %[z]\n\t"                    \
        "s_nop 7\n\t"                                                                  \
        "s_nop 7\n\t"                                                                  \
        "v_cvt_pk_bf16_f32 v60, |v52|, |v53|\n\t"                                      \
        "v_cvt_pk_bf16_f32 v61, |v54|, |v55|\n\t"                                      \
        "v_cvt_pk_bf16_f32 v62, |v56|, |v57|\n\t"                                      \
        "v_cvt_pk_bf16_f32 v63, |v58|, |v59|\n\t"                                      \
        "s_nop 3\n\t"                                                                  \
        "v_mfma_f32_16x16x32_bf16 %[acc], %[a2], v[60:63], %[acc]"                     \
        : [acc] "+v"(ACC)                                                              \
        : [f0] "v"(F0V), [f1] "v"(F1V), [a2] "v"(A2V), [b1] "v"(B1V), [z] "v"(z4)      \
        : "v52","v53","v54","v55","v56","v57","v58","v59","v60","v61","v62","v63")

// ---------------- main: 64 tokens/block, 4 waves f-split, per-XCD table replica ----------------
__global__ __launch_bounds__(256) void tbq_mfma(
    const float* __restrict__ x,
    const float* __restrict__ Wq,
    const float* __restrict__ Wo,
    const float* __restrict__ b2,
    const float* __restrict__ g1,
    const float* __restrict__ beta1,
    const float* __restrict__ g2,
    const float* __restrict__ beta2,
    const uint4* __restrict__ ws,
    float* __restrict__ out)
{
    __shared__ __align__(16) uint4 mS[64];           // 1KB  m (bf16) per token
    __shared__ __align__(16) float part[4][64][8];   // 8KB per-wave partial ffn

    const int tid  = threadIdx.x;
    const int lane = tid & 63;
    const int wv   = tid >> 6;
    const int c    = lane & 15;
    const int g    = lane >> 4;
    const int tok0 = blockIdx.x * 64;

    // per-XCD replica (round-robin block->XCD dispatch)
    const uint4* wsr = ws + (blockIdx.x & 7) * REP_STRIDE;
    const uint2* ws2 = (const uint2*)wsr;
    const float* M   = (const float*)wsr + 21248;

    // per-lane slot offsets (verified R16)
    const int o1x = (g < 2) ? (1 + c + 16 * g) : ((g == 2) ? (33 + c) : 0);   // uint2
    const int o2  = ((lane & 8) == 0) ? (1 + ((lane >> 4) << 3) + (lane & 7)) : 0;  // uint4
    const int cc0 = wv * 16;

    // ---- pipeline prologue: chunks 0,1,2 into slots 0,1,2 ----
    Frag2U F0[4], F1[4];
    FragU  A2[4];
    #pragma unroll
    for (int p = 0; p < 3; ++p) {
        const int cc = cc0 + p;
        F0[p].d = ws2[4224 + (cc * 2 + 0) * 50 + o1x];
        F1[p].d = ws2[4224 + (cc * 2 + 1) * 50 + o1x];
        A2[p].q = (wsr + cc * 33)[o2];
    }

    // ---- prefix: threads 0-63, one thread per token ----
    float h[8], m[8];
    if (tid < 64) {
        const int t = tok0 + tid;
        const float4* xr = (const float4*)(x + (size_t)t * 8);
        float4 xa = xr[0], xb = xr[1];
        float xv[8] = {xa.x, xa.y, xa.z, xa.w, xb.x, xb.y, xb.z, xb.w};

        float qm[8];
        {
            float cp = 1.0f;
            #pragma unroll
            for (int f = 0; f < 8; ++f) {
                float acc = 0.0f;
                #pragma unroll
                for (int e = 0; e < 8; ++e) acc += xv[e] * Wq[f * 8 + e];
                cp *= __cosf(acc);
                qm[f] = cp;
            }
        }
        float mu = 0.0f;
        #pragma unroll
        for (int f = 0; f < 8; ++f) {
            float acc = 0.0f;
            #pragma unroll
            for (int e = 0; e < 8; ++e) acc += qm[e] * Wo[f * 8 + e];
            h[f] = xv[f] + acc;
            mu += h[f];
        }
        mu *= 0.125f;
        float var = 0.0f;
        #pragma unroll
        for (int i = 0; i < 8; ++i) { float d = h[i] - mu; var += d * d; }
        var *= 0.125f;
        float rs = rsqrtf(var + LN_EPS);
        #pragma unroll
        for (int i = 0; i < 8; ++i) h[i] = (h[i] - mu) * rs * g1[i] + beta1[i];

        {
            float cp = 1.0f;
            #pragma unroll
            for (int i = 0; i < 8; ++i) { cp *= __cosf(h[i]); m[i] = cp; }
        }
        uint4 mq;
        mq.x = cvtpk(m[0], m[1]); mq.y = cvtpk(m[2], m[3]);
        mq.z = cvtpk(m[4], m[5]); mq.w = cvtpk(m[6], m[7]);
        mS[tid] = mq;
    }
    __syncthreads();

    // ---- B1 fragments (x16: gg<2 -> m[4gg+j], gg=2 j0 -> 1.0) ----
    Frag2U B1[4];
    #pragma unroll
    for (int T = 0; T < 4; ++T) {
        uint4 mr = mS[T * 16 + c];
        B1[T].u[0] = (g == 0) ? mr.x : ((g == 1) ? mr.z : ((g == 2) ? 0x00003F80u : 0u));
        B1[T].u[1] = (g == 0) ? mr.y : ((g == 1) ? mr.w : 0u);
    }

    f32x4 z4 = {0.f, 0.f, 0.f, 0.f};
    asm volatile("" : "+v"(z4));

    f32x4 acc[4] = {{0,0,0,0},{0,0,0,0},{0,0,0,0},{0,0,0,0}};
    asm volatile("s_nop 3" ::: "memory");   // VALU writes -> asm MFMA reads

    // ---- FFN abs-half: 16 chunks, 4-slot rotation / distance-3 prefetch ----
    #pragma unroll
    for (int i = 0; i < 16; ++i) {
        const int cur = i & 3;
        if (i + 3 < 16) {
            const int ns = (i + 3) & 3;
            const int cc = cc0 + i + 3;
            F0[ns].d = ws2[4224 + (cc * 2 + 0) * 50 + o1x];
            F1[ns].d = ws2[4224 + (cc * 2 + 1) * 50 + o1x];
            A2[ns].q = (wsr + cc * 33)[o2];
        }
        TB_A(acc[0], F0[cur].v, F1[cur].v, A2[cur].v, B1[0].v);
        TB_B(acc[1], F0[cur].v, F1[cur].v, A2[cur].v, B1[1].v);
        TB_A(acc[2], F0[cur].v, F1[cur].v, A2[cur].v, B1[2].v);
        TB_B(acc[3], F0[cur].v, F1[cur].v, A2[cur].v, B1[3].v);
    }
    asm volatile("s_nop 7\n\ts_nop 7" ::: "memory");   // MFMA writes -> LDS stores

    // ---- write partial fragments: part[wv][tok][e] ----
    if (g < 2) {
        #pragma unroll
        for (int T = 0; T < 4; ++T) {
            *(f32x4*)&part[wv][T * 16 + c][4 * g] = acc[T];
        }
    }
    __syncthreads();

    // ---- threads 0-63: reduce + M-linear + LN2 + store ----
    if (tid < 64) {
        float mb[9];
        #pragma unroll
        for (int k = 0; k < 8; ++k) mb[k] = frombf(to_bf16(m[k]));
        mb[8] = 1.0f;

        float ffnv[8];
        #pragma unroll
        for (int e = 0; e < 8; ++e) {
            float s = part[0][tid][e] + part[1][tid][e]
                    + part[2][tid][e] + part[3][tid][e];   // = 1/2 W2 |hid|
            float lin = 0.0f;
            #pragma unroll
            for (int k = 0; k < 9; ++k) lin += M[e * 9 + k] * mb[k];  // = 1/2 W2 hid
            ffnv[e] = s + lin;
        }

        float o[8];
        float mu2 = 0.0f;
        #pragma unroll
        for (int i = 0; i < 8; ++i) { o[i] = h[i] + ffnv[i] + b2[i]; mu2 += o[i]; }
        mu2 *= 0.125f;
        float v2 = 0.0f;
        #pragma unroll
        for (int i = 0; i < 8; ++i) { float d = o[i] - mu2; v2 += d * d; }
        v2 *= 0.125f;
        float rs2 = rsqrtf(v2 + LN_EPS);

        float res[8];
        #pragma unroll
        for (int i = 0; i < 8; ++i) res[i] = (o[i] - mu2) * rs2 * g2[i] + beta2[i];

        float4* orow = (float4*)(out + (size_t)(tok0 + tid) * 8);
        orow[0] = make_float4(res[0], res[1], res[2], res[3]);
        orow[1] = make_float4(res[4], res[5], res[6], res[7]);
    }
}

extern "C" void kernel_launch(void* const* d_in, const int* in_sizes, int n_in,
                              void* d_out, int out_size, void* d_ws, size_t ws_size,
                              hipStream_t stream) {
    const float* x     = (const float*)d_in[0];
    const float* Wq    = (const float*)d_in[1];
    const float* Wo    = (const float*)d_in[2];
    const float* W1    = (const float*)d_in[3];
    const float* b1    = (const float*)d_in[4];
    const float* W2    = (const float*)d_in[5];
    const float* b2    = (const float*)d_in[6];
    const float* g1    = (const float*)d_in[7];
    const float* beta1 = (const float*)d_in[8];
    const float* g2    = (const float*)d_in[9];
    const float* beta2 = (const float*)d_in[10];
    float* out = (float*)d_out;
    uint4* ws = (uint4*)d_ws;   // 8 replicas x 86 KB = 688 KB

    tbq_prep<<<52 * 8, 256, 0, stream>>>(W1, b1, W2, ws);   // 8 replicas

    const int ntok = in_sizes[0] / 8;      // 131072
    const int grid = ntok / 64;            // 2048 blocks, 4 waves f-split
    tbq_mfma<<<grid, 256, 0, stream>>>(x, Wq, Wo, b2, g1, beta1, g2, beta2, ws, out);
}

// Round 20
// 33.403 us; speedup vs baseline: 1.1619x; 1.1619x over previous
//
#include <hip/hip_runtime.h>
#include <hip/hip_bf16.h>

#define FFN 2048
#define LN_EPS 1e-5f

typedef __attribute__((ext_vector_type(8))) short bf16x8;
typedef __attribute__((ext_vector_type(4))) short bf16x4;
typedef __attribute__((ext_vector_type(4))) float f32x4;

union FragU  { bf16x8 v; unsigned u[4]; uint4 q; };
union Frag2U { bf16x4 v; unsigned u[2]; uint2 d; };

static __device__ __forceinline__ unsigned cvtpk(float lo, float hi) {
    unsigned r;
    asm("v_cvt_pk_bf16_f32 %0, %1, %2" : "=v"(r) : "v"(lo), "v"(hi));
    return r;
}
static __device__ __forceinline__ ushort to_bf16(float f) {   // RNE, finite inputs
    unsigned u = __float_as_uint(f);
    u += 0x7fffu + ((u >> 16) & 1u);
    return (ushort)(u >> 16);
}
static __device__ __forceinline__ float frombf(ushort u) {
    return __uint_as_float((unsigned)u << 16);
}
static __device__ __forceinline__ unsigned pk2u(ushort a, ushort b) {
    return (unsigned)a | ((unsigned)b << 16);
}

// ws layout (R16-verified):
//  uint4  [0 .. 2111]     pW2 recs (33 uint4 each; bf16(W2/2), permuted k)
//  uint2  [4224 .. 10623] pW1x16 recs (50 uint2 each; W1 + b1 row, x16 A-frag layout)
//  float  [21248..21319]  M[e*9+k]
__global__ __launch_bounds__(256) void tbq_prep(
    const float* __restrict__ W1, const float* __restrict__ b1,
    const float* __restrict__ W2, uint4* __restrict__ ws)
{
    const int b = blockIdx.x;
    if (b < 34) {
        const int idx = b * 256 + threadIdx.x;
        if (idx < 2112) {                       // pW2 records
            const int rec = idx / 33, r = idx % 33;
            ushort v[8] = {0,0,0,0,0,0,0,0};
            if (r) {
                const int l32 = r - 1, g = l32 >> 3, c = l32 & 7, cc = rec;
                #pragma unroll
                for (int j = 0; j < 8; ++j) {
                    const int fl = 4 * g + (j & 3) + 16 * (j >> 2);
                    v[j] = to_bf16(0.5f * W2[c * FFN + cc * 32 + fl]);
                }
            }
            union { ushort s[8]; uint4 q; } pk;
            #pragma unroll
            for (int j = 0; j < 8; ++j) pk.s[j] = v[j];
            ws[idx] = pk.q;
        } else if (idx < 8512) {                // pW1x16 records
            const int i2 = idx - 2112;
            const int rec = i2 / 50, r = i2 % 50;
            const int s = rec & 1, cc = rec >> 1;
            uint2 val = make_uint2(0u, 0u);
            if (r >= 1 && r <= 32) {
                const int l32 = r - 1, c = l32 & 15, gg = l32 >> 4;
                const int f = cc * 32 + s * 16 + c;
                val.x = pk2u(to_bf16(W1[f * 8 + 4 * gg + 0]), to_bf16(W1[f * 8 + 4 * gg + 1]));
                val.y = pk2u(to_bf16(W1[f * 8 + 4 * gg + 2]), to_bf16(W1[f * 8 + 4 * gg + 3]));
            } else if (r >= 33 && r <= 48) {
                const int c = r - 33;
                const int f = cc * 32 + s * 16 + c;
                val.x = pk2u(to_bf16(b1[f]), 0);
            }
            ((uint2*)ws)[4224 + i2] = val;
        }
    } else {                                    // M reduction
        const int w = (b - 34) * 4 + (threadIdx.x >> 6);   // 0..71
        const int lane = threadIdx.x & 63;
        const int e = w / 9, k = w % 9;
        float acc = 0.0f;
        #pragma unroll 4
        for (int i = 0; i < 32; ++i) {
            const int f = lane + i * 64;
            const float w2v = frombf(to_bf16(0.5f * W2[e * FFN + f]));
            const float ov  = (k < 8) ? frombf(to_bf16(W1[f * 8 + k]))
                                      : frombf(to_bf16(b1[f]));
            acc += w2v * ov;
        }
        #pragma unroll
        for (int m = 32; m >= 1; m >>= 1) acc += __shfl_xor(acc, m, 64);
        if (lane == 0) ((float*)ws)[21248 + w] = acc;
    }
}

// T-bodies (R16-verified): 2x GEMM1(16x16x16, K=9 of 16) -> |.|+bf16 pack -> GEMM2(16x16x32).
#define TB_A(ACC, F0V, F1V, A2V, B1V)                                                  \
    asm volatile(                                                                      \
        "v_mfma_f32_16x16x16_bf16 v[40:43], %[f0], %[b1], %[z]\n\t"                    \
        "v_mfma_f32_16x16x16_bf16 v[44:47], %[f1], %[b1], %[z]\n\t"                    \
        "s_nop 7\n\t"                                                                  \
        "s_nop 7\n\t"                                                                  \
        "v_cvt_pk_bf16_f32 v48, |v40|, |v41|\n\t"                                      \
        "v_cvt_pk_bf16_f32 v49, |v42|, |v43|\n\t"                                      \
        "v_cvt_pk_bf16_f32 v50, |v44|, |v45|\n\t"                                      \
        "v_cvt_pk_bf16_f32 v51, |v46|, |v47|\n\t"                                      \
        "s_nop 3\n\t"                                                                  \
        "v_mfma_f32_16x16x32_bf16 %[acc], %[a2], v[48:51], %[acc]"                     \
        : [acc] "+v"(ACC)                                                              \
        : [f0] "v"(F0V), [f1] "v"(F1V), [a2] "v"(A2V), [b1] "v"(B1V), [z] "v"(z4)      \
        : "v40","v41","v42","v43","v44","v45","v46","v47","v48","v49","v50","v51")

#define TB_B(ACC, F0V, F1V, A2V, B1V)                                                  \
    asm volatile(                                                                      \
        "v_mfma_f32_16x16x16_bf16 v[52:55], %[f0], %[b1], %[z]\n\t"                    \
        "v_mfma_f32_16x16x16_bf16 v[56:59], %[f1], %[b1], %[z]\n\t"                    \
        "s_nop 7\n\t"                                                                  \
        "s_nop 7\n\t"                                                                  \
        "v_cvt_pk_bf16_f32 v60, |v52|, |v53|\n\t"                                      \
        "v_cvt_pk_bf16_f32 v61, |v54|, |v55|\n\t"                                      \
        "v_cvt_pk_bf16_f32 v62, |v56|, |v57|\n\t"                                      \
        "v_cvt_pk_bf16_f32 v63, |v58|, |v59|\n\t"                                      \
        "s_nop 3\n\t"                                                                  \
        "v_mfma_f32_16x16x32_bf16 %[acc], %[a2], v[60:63], %[acc]"                     \
        : [acc] "+v"(ACC)                                                              \
        : [f0] "v"(F0V), [f1] "v"(F1V), [a2] "v"(A2V), [b1] "v"(B1V), [z] "v"(z4)      \
        : "v52","v53","v54","v55","v56","v57","v58","v59","v60","v61","v62","v63")

// ---------------- main: 64 tokens/block, 4 waves f-split ----------------
__global__ __launch_bounds__(256) void tbq_mfma(
    const float* __restrict__ x,
    const float* __restrict__ Wq,
    const float* __restrict__ Wo,
    const float* __restrict__ b2,
    const float* __restrict__ g1,
    const float* __restrict__ beta1,
    const float* __restrict__ g2,
    const float* __restrict__ beta2,
    const uint4* __restrict__ ws,
    float* __restrict__ out)
{
    __shared__ __align__(16) uint4 mS[64];           // 1KB  m (bf16) per token
    __shared__ __align__(16) float part[4][64][8];   // 8KB per-wave partial ffn

    const int tid  = threadIdx.x;
    const int lane = tid & 63;
    const int wv   = tid >> 6;
    const int c    = lane & 15;
    const int g    = lane >> 4;
    const int tok0 = blockIdx.x * 64;

    const uint2* ws2 = (const uint2*)ws;
    const float* M   = (const float*)ws + 21248;

    // per-lane slot offsets (verified R16)
    const int o1x = (g < 2) ? (1 + c + 16 * g) : ((g == 2) ? (33 + c) : 0);   // uint2
    const int o2  = ((lane & 8) == 0) ? (1 + ((lane >> 4) << 3) + (lane & 7)) : 0;  // uint4
    const int cc0 = wv * 16;

    // ---- pipeline prologue: chunks 0,1,2 into slots 0,1,2 ----
    Frag2U F0[4], F1[4];
    FragU  A2[4];
    #pragma unroll
    for (int p = 0; p < 3; ++p) {
        const int cc = cc0 + p;
        F0[p].d = ws2[4224 + (cc * 2 + 0) * 50 + o1x];
        F1[p].d = ws2[4224 + (cc * 2 + 1) * 50 + o1x];
        A2[p].q = (ws + cc * 33)[o2];
    }

    // ---- prefix: threads 0-63, one thread per token ----
    float h[8], m[8];
    if (tid < 64) {
        const int t = tok0 + tid;
        const float4* xr = (const float4*)(x + (size_t)t * 8);
        float4 xa = xr[0], xb = xr[1];
        float xv[8] = {xa.x, xa.y, xa.z, xa.w, xb.x, xb.y, xb.z, xb.w};

        float qm[8];
        {
            float cp = 1.0f;
            #pragma unroll
            for (int f = 0; f < 8; ++f) {
                float acc = 0.0f;
                #pragma unroll
                for (int e = 0; e < 8; ++e) acc += xv[e] * Wq[f * 8 + e];
                cp *= __cosf(acc);
                qm[f] = cp;
            }
        }
        float mu = 0.0f;
        #pragma unroll
        for (int f = 0; f < 8; ++f) {
            float acc = 0.0f;
            #pragma unroll
            for (int e = 0; e < 8; ++e) acc += qm[e] * Wo[f * 8 + e];
            h[f] = xv[f] + acc;
            mu += h[f];
        }
        mu *= 0.125f;
        float var = 0.0f;
        #pragma unroll
        for (int i = 0; i < 8; ++i) { float d = h[i] - mu; var += d * d; }
        var *= 0.125f;
        float rs = rsqrtf(var + LN_EPS);
        #pragma unroll
        for (int i = 0; i < 8; ++i) h[i] = (h[i] - mu) * rs * g1[i] + beta1[i];

        {
            float cp = 1.0f;
            #pragma unroll
            for (int i = 0; i < 8; ++i) { cp *= __cosf(h[i]); m[i] = cp; }
        }
        uint4 mq;
        mq.x = cvtpk(m[0], m[1]); mq.y = cvtpk(m[2], m[3]);
        mq.z = cvtpk(m[4], m[5]); mq.w = cvtpk(m[6], m[7]);
        mS[tid] = mq;
    }
    __syncthreads();

    // ---- B1 fragments (x16: gg<2 -> m[4gg+j], gg=2 j0 -> 1.0) ----
    Frag2U B1[4];
    #pragma unroll
    for (int T = 0; T < 4; ++T) {
        uint4 mr = mS[T * 16 + c];
        B1[T].u[0] = (g == 0) ? mr.x : ((g == 1) ? mr.z : ((g == 2) ? 0x00003F80u : 0u));
        B1[T].u[1] = (g == 0) ? mr.y : ((g == 1) ? mr.w : 0u);
    }

    f32x4 z4 = {0.f, 0.f, 0.f, 0.f};
    asm volatile("" : "+v"(z4));

    f32x4 acc[4] = {{0,0,0,0},{0,0,0,0},{0,0,0,0},{0,0,0,0}};
    asm volatile("s_nop 3" ::: "memory");   // VALU writes -> asm MFMA reads

    // ---- FFN abs-half: 16 chunks, 4-slot rotation / distance-3 prefetch ----
    #pragma unroll
    for (int i = 0; i < 16; ++i) {
        const int cur = i & 3;
        if (i + 3 < 16) {
            const int ns = (i + 3) & 3;
            const int cc = cc0 + i + 3;
            F0[ns].d = ws2[4224 + (cc * 2 + 0) * 50 + o1x];
            F1[ns].d = ws2[4224 + (cc * 2 + 1) * 50 + o1x];
            A2[ns].q = (ws + cc * 33)[o2];
        }
        __builtin_amdgcn_s_setprio(1);
        TB_A(acc[0], F0[cur].v, F1[cur].v, A2[cur].v, B1[0].v);
        TB_B(acc[1], F0[cur].v, F1[cur].v, A2[cur].v, B1[1].v);
        TB_A(acc[2], F0[cur].v, F1[cur].v, A2[cur].v, B1[2].v);
        TB_B(acc[3], F0[cur].v, F1[cur].v, A2[cur].v, B1[3].v);
        __builtin_amdgcn_s_setprio(0);
    }
    asm volatile("s_nop 7\n\ts_nop 7" ::: "memory");   // MFMA writes -> LDS stores

    // ---- write partial fragments: part[wv][tok][e] ----
    if (g < 2) {
        #pragma unroll
        for (int T = 0; T < 4; ++T) {
            *(f32x4*)&part[wv][T * 16 + c][4 * g] = acc[T];
        }
    }
    __syncthreads();

    // ---- threads 0-63: reduce + M-linear + LN2 + store ----
    if (tid < 64) {
        float mb[9];
        #pragma unroll
        for (int k = 0; k < 8; ++k) mb[k] = frombf(to_bf16(m[k]));
        mb[8] = 1.0f;

        float ffnv[8];
        #pragma unroll
        for (int e = 0; e < 8; ++e) {
            float s = part[0][tid][e] + part[1][tid][e]
                    + part[2][tid][e] + part[3][tid][e];   // = 1/2 W2 |hid|
            float lin = 0.0f;
            #pragma unroll
            for (int k = 0; k < 9; ++k) lin += M[e * 9 + k] * mb[k];  // = 1/2 W2 hid
            ffnv[e] = s + lin;
        }

        float o[8];
        float mu2 = 0.0f;
        #pragma unroll
        for (int i = 0; i < 8; ++i) { o[i] = h[i] + ffnv[i] + b2[i]; mu2 += o[i]; }
        mu2 *= 0.125f;
        float v2 = 0.0f;
        #pragma unroll
        for (int i = 0; i < 8; ++i) { float d = o[i] - mu2; v2 += d * d; }
        v2 *= 0.125f;
        float rs2 = rsqrtf(v2 + LN_EPS);

        float res[8];
        #pragma unroll
        for (int i = 0; i < 8; ++i) res[i] = (o[i] - mu2) * rs2 * g2[i] + beta2[i];

        float4* orow = (float4*)(out + (size_t)(tok0 + tid) * 8);
        orow[0] = make_float4(res[0], res[1], res[2], res[3]);
        orow[1] = make_float4(res[4], res[5], res[6], res[7]);
    }
}

extern "C" void kernel_launch(void* const* d_in, const int* in_sizes, int n_in,
                              void* d_out, int out_size, void* d_ws, size_t ws_size,
                              hipStream_t stream) {
    const float* x     = (const float*)d_in[0];
    const float* Wq    = (const float*)d_in[1];
    const float* Wo    = (const float*)d_in[2];
    const float* W1    = (const float*)d_in[3];
    const float* b1    = (const float*)d_in[4];
    const float* W2    = (const float*)d_in[5];
    const float* b2    = (const float*)d_in[6];
    const float* g1    = (const float*)d_in[7];
    const float* beta1 = (const float*)d_in[8];
    const float* g2    = (const float*)d_in[9];
    const float* beta2 = (const float*)d_in[10];
    float* out = (float*)d_out;
    uint4* ws = (uint4*)d_ws;   // ~86 KB used

    tbq_prep<<<52, 256, 0, stream>>>(W1, b1, W2, ws);   // 34 rec-blocks + 18 M-blocks

    const int ntok = in_sizes[0] / 8;      // 131072
    const int grid = ntok / 64;            // 2048 blocks, 4 waves f-split
    tbq_mfma<<<grid, 256, 0, stream>>>(x, Wq, Wo, b2, g1, beta1, g2, beta2, ws, out);
}